// Round 5
// baseline (672.304 us; speedup 1.0000x reference)
//
#include <hip/hip_runtime.h>
#include <math.h>

#define NA 16384
#define ER 524288
#define EB 32768
#define ET 557056
#define INV_NORM 0.17149858514250882f   // 1/sqrt((ER+EB)/NA) = 1/sqrt(34)
#define SQRT3 1.7320508075688772f
#define RB_STEP (1.5f/9.0f)

// Pin a value into a VGPR (prevents the compiler sinking weight loads into the loop)
#define KEEP(x) asm volatile("" : "+v"(x))

typedef float nfloat4 __attribute__((ext_vector_type(4)));

__device__ __forceinline__ float sigmoidf_(float x) { return 1.f / (1.f + __expf(-x)); }

__device__ __forceinline__ float rfl_f(float x) {
  return __int_as_float(__builtin_amdgcn_readfirstlane(__float_as_int(x)));
}

__device__ __forceinline__ int edge_dst(int e, const int* __restrict__ rad, const int* __restrict__ bon) {
  return (e < ER) ? rad[ER + e] : bon[EB + (e - ER)];
}

// ---------------- CSR build ----------------
__global__ void k_zero(int* __restrict__ count) {
  count[blockIdx.x * 256 + threadIdx.x] = 0;
}

__global__ void k_hist(const int* __restrict__ rad, const int* __restrict__ bon, int* __restrict__ count) {
  int e = blockIdx.x * 256 + threadIdx.x;
  atomicAdd(&count[edge_dst(e, rad, bon)], 1);
}

__global__ void k_scan(int* __restrict__ count, int* __restrict__ offsets) {
  __shared__ int part[256];
  int t = threadIdx.x;
  int base = t * 64;
  int s = 0;
  for (int j = 0; j < 64; ++j) s += count[base + j];
  part[t] = s;
  __syncthreads();
  for (int off = 1; off < 256; off <<= 1) {
    int v = (t >= off) ? part[t - off] : 0;
    __syncthreads();
    part[t] += v;
    __syncthreads();
  }
  int run = part[t] - s;  // exclusive prefix
  for (int j = 0; j < 64; ++j) {
    int c = count[base + j];
    offsets[base + j] = run;
    count[base + j] = run;  // becomes cursor for k_fill
    run += c;
  }
  if (t == 255) offsets[NA] = run;
}

__global__ void k_fill(const int* __restrict__ rad, const int* __restrict__ bon,
                       int* __restrict__ cursor, int* __restrict__ sorted) {
  int e = blockIdx.x * 256 + threadIdx.x;
  int d = edge_dst(e, rad, bon);
  int slot = atomicAdd(&cursor[d], 1);
  sorted[slot] = e;
}

// ---------------- per-edge record precompute ----------------
// record[idx] (48B, CSR slot order): {src|(isBond<<16), Y0,Y1,Y2}, {rb0..3}, {rb4..7}
__global__ void k_edge_pre(const float* __restrict__ pos,
                           const int* __restrict__ rad, const int* __restrict__ bon,
                           const int* __restrict__ sorted, float4* __restrict__ rec) {
  int idx = blockIdx.x * 256 + threadIdx.x;
  int e = sorted[idx];
  int src, dst, flag;
  if (e < ER) { src = rad[e]; dst = rad[ER + e]; flag = 0; }
  else        { src = bon[e - ER]; dst = bon[EB + e - ER]; flag = 1 << 16; }
  float dx = pos[src * 3] - pos[dst * 3];
  float dy = pos[src * 3 + 1] - pos[dst * 3 + 1];
  float dz = pos[src * 3 + 2] - pos[dst * 3 + 2];
  float dist = sqrtf(dx * dx + dy * dy + dz * dz + 1e-12f);
  float inv = 1.f / dist;
  float4* rp = rec + (size_t)idx * 3;
  rp[0] = make_float4(__int_as_float(src | flag), SQRT3 * dx * inv, SQRT3 * dy * inv, SQRT3 * dz * inv);
  float rb[8];
#pragma unroll
  for (int k = 0; k < 8; ++k) {
    float diff = (dist - (k + 1) * RB_STEP) * (1.f / RB_STEP);
    rb[k] = 1.12f * __expf(-diff * diff);
  }
  rp[1] = make_float4(rb[0], rb[1], rb[2], rb[3]);
  rp[2] = make_float4(rb[4], rb[5], rb[6], rb[7]);
}

// ---------------- embedding ----------------
__global__ void k_embed(const float* __restrict__ atom_tab, const int* __restrict__ types,
                        const float* __restrict__ ns0_w, const float* __restrict__ cnoise,
                        float* __restrict__ s_feat) {
  int tid = blockIdx.x * 256 + threadIdx.x;
  int n = tid >> 6, c = tid & 63;
  float cn = cnoise[0];
  s_feat[tid] = atom_tab[types[n] * 64 + c] * (1.f + cn * ns0_w[c]);
}

// ---------------- initial aggregation (wave per node, lane = channel) ----------------
__global__ __launch_bounds__(256, 5) void k_agg0(
    const float* __restrict__ bond_tab,
    const float* __restrict__ We0, const float* __restrict__ We1,
    const int* __restrict__ offsets, const float* __restrict__ recf,
    const float* __restrict__ s_feat,
    float* __restrict__ a_s, float* __restrict__ a_v) {
  int lane = threadIdx.x & 63;
  int n = blockIdx.x * 4 + (threadIdx.x >> 6);
  int c = lane;
  float w0r[8], w1r[8];
  float w0b0 = 0, w0b1 = 0, w1b0 = 0, w1b1 = 0;
#pragma unroll
  for (int k = 0; k < 8; ++k) {
    w0r[k] = We0[(8 + k) * 64 + c];
    w1r[k] = We1[(8 + k) * 64 + c];
    float bt0 = bond_tab[k], bt1 = bond_tab[8 + k];
    float c0 = We0[k * 64 + c], c1 = We1[k * 64 + c];
    w0b0 += bt0 * c0; w0b1 += bt1 * c0;
    w1b0 += bt0 * c1; w1b1 += bt1 * c1;
  }
#pragma unroll
  for (int k = 0; k < 8; ++k) { KEEP(w0r[k]); KEEP(w1r[k]); }
  KEEP(w0b0); KEEP(w0b1); KEEP(w1b0); KEEP(w1b1);

  float acc = 0, a0 = 0, a1 = 0, a2 = 0;
  int beg = __builtin_amdgcn_readfirstlane(offsets[n]);
  int end = __builtin_amdgcn_readfirstlane(offsets[n + 1]);
#pragma unroll 2
  for (int idx = beg; idx < end; ++idx) {
    // wave-uniform record: SMEM-friendly (uniform address, readonly)
    const float* rp = recf + (size_t)idx * 12;
    float r[12];
#pragma unroll
    for (int j = 0; j < 12; ++j) r[j] = rp[j];
    int senc = __builtin_amdgcn_readfirstlane(__float_as_int(r[0]));
    int src = senc & 0xFFFF;
    bool isB = senc >= (1 << 16);
    float y0 = rfl_f(r[1]), y1 = rfl_f(r[2]), y2 = rfl_f(r[3]);
    // gather with uniform (SGPR) base + lane offset
    const float* pS = s_feat + ((size_t)src << 6);
    float sv = pS[c];
    float w0 = isB ? w0b1 : w0b0;
    float w1 = isB ? w1b1 : w1b0;
#pragma unroll
    for (int k = 0; k < 8; ++k) {
      float rb = rfl_f(r[4 + k]);
      w0 += rb * w0r[k];
      w1 += rb * w1r[k];
    }
    acc += w0 * sv;
    float t = w1 * sv;
    a0 += t * y0; a1 += t * y1; a2 += t * y2;
  }
  a_s[n * 64 + c] = acc * INV_NORM;
  float* avp = a_v + (size_t)n * 192 + c * 3;
  avp[0] = a0 * INV_NORM; avp[1] = a1 * INV_NORM; avp[2] = a2 * INV_NORM;
}

// ---------------- initial projections (merged sh + vh) ----------------
__global__ void k_init(const float* __restrict__ a_s, const float* __restrict__ s_feat,
                       const float* __restrict__ Ws0, const float* __restrict__ Wself0,
                       const float* __restrict__ a_v, const float* __restrict__ Wv0,
                       float* __restrict__ sh, float* __restrict__ vh) {
  int b = blockIdx.x;
  if (b < NA * 64 / 256) {
    int tid = b * 256 + threadIdx.x;
    int n = tid >> 6, d = tid & 63;
    float acc = 0;
    const float* as = a_s + n * 64;
    const float* sp = s_feat + n * 64;
    for (int c = 0; c < 64; ++c)
      acc += as[c] * Ws0[c * 64 + d] + sp[c] * Wself0[c * 64 + d];
    sh[tid] = acc;
  } else {
    int tid = (b - NA * 64 / 256) * 256 + threadIdx.x;
    int n = tid >> 5, d = tid & 31;
    float a0 = 0, a1 = 0, a2 = 0;
    const float* av = a_v + (size_t)n * 192;
    for (int c = 0; c < 64; ++c) {
      float w = Wv0[c * 32 + d];
      a0 += av[c * 3] * w; a1 += av[c * 3 + 1] * w; a2 += av[c * 3 + 2] * w;
    }
    float* o = vh + (size_t)n * 128 + d * 4;  // padded [n][32][4]
    o[0] = a0; o[1] = a1; o[2] = a2;
  }
}

// ---------------- layer aggregation (wave per node) ----------------
__global__ __launch_bounds__(256, 5) void k_agg_layer(
    const float* __restrict__ cnoise, const float* __restrict__ bond_tab,
    const float* __restrict__ Wss, const float* __restrict__ Wvs,
    const float* __restrict__ Wsv, const float* __restrict__ Wvv,
    const float* __restrict__ Wvx, const float* __restrict__ nsw,
    const int* __restrict__ offsets, const float* __restrict__ recf,
    const float* __restrict__ sh_in, const float* __restrict__ vh_in,
    float* __restrict__ a_s, float* __restrict__ a_v) {
  int lane = threadIdx.x & 63;
  int n = blockIdx.x * 4 + (threadIdx.x >> 6);
  int c = lane;
  int vc = lane & 31;
  bool low = lane < 32;
  float cn = cnoise[0];

  float rss[8], rsv[8], rva[8], rvb[8];
  float bss0 = 0, bss1 = 0, bsv0 = 0, bsv1 = 0, bva0 = 0, bva1 = 0, bvb0 = 0, bvb1 = 0;
#pragma unroll
  for (int k = 0; k < 8; ++k) {
    float wss_lo = Wss[k * 64 + c], wss_hi = Wss[(8 + k) * 64 + c];
    float wsv_lo = Wsv[k * 64 + c], wsv_hi = Wsv[(8 + k) * 64 + c];
    float wa_lo = low ? Wvs[k * 32 + vc] : Wvx[k * 32 + vc];
    float wa_hi = low ? Wvs[(8 + k) * 32 + vc] : Wvx[(8 + k) * 32 + vc];
    float wb_lo = low ? Wvv[k * 32 + vc] : 0.f;
    float wb_hi = low ? Wvv[(8 + k) * 32 + vc] : 0.f;
    float bt0 = bond_tab[k], bt1 = bond_tab[8 + k];
    rss[k] = wss_hi; rsv[k] = wsv_hi; rva[k] = wa_hi; rvb[k] = wb_hi;
    bss0 += bt0 * wss_lo; bss1 += bt1 * wss_lo;
    bsv0 += bt0 * wsv_lo; bsv1 += bt1 * wsv_lo;
    bva0 += bt0 * wa_lo;  bva1 += bt1 * wa_lo;
    bvb0 += bt0 * wb_lo;  bvb1 += bt1 * wb_lo;
  }
#pragma unroll
  for (int k = 0; k < 8; ++k) { KEEP(rss[k]); KEEP(rsv[k]); KEEP(rva[k]); KEEP(rvb[k]); }
  KEEP(bss0); KEEP(bss1); KEEP(bsv0); KEEP(bsv1);
  KEEP(bva0); KEEP(bva1); KEEP(bvb0); KEEP(bvb1);

  float scale_s = 1.f + cn * nsw[c];
  float scale_v = 1.f + cn * nsw[64 + vc];

  float ms = 0;                    // sum w_ss*sh        (scale_s folded at store)
  float av0 = 0, av1 = 0, av2 = 0; // sum w_sv*sh*Y      (scale_s folded)
  float ms2 = 0;                   // low: sum w_vs*(v.Y) (scale_v folded)
  float b0 = 0, b1 = 0, b2 = 0;    // low: w_vv*v ; high: w_vx*cross(v,Y) (scale_v folded)
  int beg = __builtin_amdgcn_readfirstlane(offsets[n]);
  int end = __builtin_amdgcn_readfirstlane(offsets[n + 1]);
#pragma unroll 2
  for (int idx = beg; idx < end; ++idx) {
    // wave-uniform record load (SMEM-friendly)
    const float* rp = recf + (size_t)idx * 12;
    float r[12];
#pragma unroll
    for (int j = 0; j < 12; ++j) r[j] = rp[j];
    int senc = __builtin_amdgcn_readfirstlane(__float_as_int(r[0]));
    int src = senc & 0xFFFF;
    bool isB = senc >= (1 << 16);
    float y0 = rfl_f(r[1]), y1 = rfl_f(r[2]), y2 = rfl_f(r[3]);
    // gathers: uniform SGPR base + lane offset
    const float* pS = sh_in + ((size_t)src << 6);
    float ss = pS[c];
    const nfloat4* pV = (const nfloat4*)(vh_in + ((size_t)src << 7));
    nfloat4 v4 = pV[vc];
    float wS  = isB ? bss1 : bss0;
    float wSV = isB ? bsv1 : bsv0;
    float wA  = isB ? bva1 : bva0;
    float wB  = isB ? bvb1 : bvb0;
#pragma unroll
    for (int k = 0; k < 8; ++k) {
      float rb = rfl_f(r[4 + k]);
      wS  += rb * rss[k];
      wSV += rb * rsv[k];
      wA  += rb * rva[k];
      wB  += rb * rvb[k];
    }
    float v0 = v4.x, v1 = v4.y, v2 = v4.z;
    ms += wS * ss;
    float t = wSV * ss;
    av0 += t * y0; av1 += t * y1; av2 += t * y2;
    float vdot = v0 * y0 + v1 * y1 + v2 * y2;
    ms2 += wA * vdot;  // garbage on high lanes, never written
    float cx = v1 * y2 - v2 * y1;
    float cy = v2 * y0 - v0 * y2;
    float cz = v0 * y1 - v1 * y0;
    float m0 = low ? v0 : cx;
    float m1 = low ? v1 : cy;
    float m2 = low ? v2 : cz;
    float wM = low ? wB : wA;
    b0 += wM * m0; b1 += wM * m1; b2 += wM * m2;
  }
  float fs = scale_s * INV_NORM;
  float fv = scale_v * INV_NORM;
  a_s[n * 96 + c] = ms * fs;
  float* avn = a_v + (size_t)n * 384;
  avn[c * 3] = av0 * fs; avn[c * 3 + 1] = av1 * fs; avn[c * 3 + 2] = av2 * fs;
  if (low) {
    a_s[n * 96 + 64 + vc] = ms2 * fv;
    avn[(64 + vc) * 3] = b0 * fv;
    avn[(64 + vc) * 3 + 1] = b1 * fv;
    avn[(64 + vc) * 3 + 2] = b2 * fv;
  } else {
    avn[(96 + vc) * 3] = b0 * fv;
    avn[(96 + vc) * 3 + 1] = b1 * fv;
    avn[(96 + vc) * 3 + 2] = b2 * fv;
  }
}

// ---------------- mixing / self / skip (merged s + v) ----------------
__global__ void k_mix(const float* __restrict__ a_s, const float* __restrict__ sh_in,
                      const float* __restrict__ Wmix_s, const float* __restrict__ Wself_s,
                      const float* __restrict__ a_v, const float* __restrict__ vh_in,
                      const float* __restrict__ Wmix_v, const float* __restrict__ Wself_v,
                      const float* __restrict__ nsw, const float* __restrict__ skw,
                      const float* __restrict__ skb, const float* __restrict__ cnoise,
                      float* __restrict__ sh_out, float* __restrict__ vh_out) {
  int b = blockIdx.x;
  float cn = cnoise[0];
  if (b < NA * 64 / 256) {
    int tid = b * 256 + threadIdx.x;
    int n = tid >> 6, d = tid & 63;
    float acc = 0;
    const float* as = a_s + n * 96;
    for (int cc = 0; cc < 96; ++cc) acc += as[cc] * Wmix_s[cc * 64 + d];
    const float* sp = sh_in + n * 64;
    for (int cc = 0; cc < 64; ++cc) acc += sp[cc] * (1.f + cn * nsw[cc]) * Wself_s[cc * 64 + d];
    float g1 = sigmoidf_(skb[d] + cn * skw[d]);
    float g2 = sigmoidf_(skb[64 + d] + cn * skw[64 + d]);
    sh_out[tid] = g1 * sh_in[tid] + g2 * acc;
  } else {
    int tid = (b - NA * 64 / 256) * 256 + threadIdx.x;
    int n = tid >> 5, d = tid & 31;
    float a0 = 0, a1 = 0, a2 = 0;
    const float* av = a_v + (size_t)n * 384;
    for (int cc = 0; cc < 128; ++cc) {
      float w = Wmix_v[cc * 32 + d];
      a0 += av[cc * 3] * w; a1 += av[cc * 3 + 1] * w; a2 += av[cc * 3 + 2] * w;
    }
    const float* vp = vh_in + (size_t)n * 128;
    for (int cc = 0; cc < 32; ++cc) {
      float w = Wself_v[cc * 32 + d] * (1.f + cn * nsw[64 + cc]);
      a0 += vp[cc * 4] * w; a1 += vp[cc * 4 + 1] * w; a2 += vp[cc * 4 + 2] * w;
    }
    float g3 = sigmoidf_(skb[128 + d] + cn * skw[128 + d]);
    float g4 = sigmoidf_(skb[160 + d] + cn * skw[160 + d]);
    float* o = vh_out + (size_t)n * 128 + d * 4;
    const float* vi = vh_in + (size_t)n * 128 + d * 4;
    o[0] = g3 * vi[0] + g4 * a0;
    o[1] = g3 * vi[1] + g4 * a1;
    o[2] = g3 * vi[2] + g4 * a2;
  }
}

// ---------------- output ----------------
__global__ void k_out(const float* __restrict__ vh, const float* __restrict__ w_out,
                      const float* __restrict__ gain, float* __restrict__ out) {
  int tid = blockIdx.x * 256 + threadIdx.x;  // < NA*3
  int n = tid / 3, i = tid - n * 3;
  float acc = 0;
  for (int c = 0; c < 32; ++c) acc += vh[(size_t)n * 128 + c * 4 + i] * w_out[c];
  out[tid] = acc * gain[0];
}

extern "C" void kernel_launch(void* const* d_in, const int* in_sizes, int n_in,
                              void* d_out, int out_size, void* d_ws, size_t ws_size,
                              hipStream_t stream) {
  (void)in_sizes; (void)n_in; (void)out_size; (void)ws_size;
  const float* pos     = (const float*)d_in[0];
  const float* cn      = (const float*)d_in[1];
  const int*   types   = (const int*)d_in[2];
  const int*   rad     = (const int*)d_in[3];
  const int*   bon     = (const int*)d_in[4];
  const float* atom_tab= (const float*)d_in[5];
  const float* bond_tab= (const float*)d_in[6];
  const float* ns0_w   = (const float*)d_in[7];
  const float* We0     = (const float*)d_in[8];
  const float* We1     = (const float*)d_in[9];
  const float* Wself0  = (const float*)d_in[10];
  const float* Ws0     = (const float*)d_in[11];
  const float* Wv0     = (const float*)d_in[12];
  const float* ns_w    = (const float*)d_in[13];
  const float* We_ss   = (const float*)d_in[14];
  const float* We_vs   = (const float*)d_in[15];
  const float* We_sv   = (const float*)d_in[16];
  const float* We_vv   = (const float*)d_in[17];
  const float* We_vx   = (const float*)d_in[18];
  const float* Wmix_s  = (const float*)d_in[19];
  const float* Wmix_v  = (const float*)d_in[20];
  const float* Wself_s = (const float*)d_in[21];
  const float* Wself_v = (const float*)d_in[22];
  const float* skip_w  = (const float*)d_in[23];
  const float* skip_b  = (const float*)d_in[24];
  const float* w_out   = (const float*)d_in[25];
  const float* gain    = (const float*)d_in[26];

  char* ws = (char*)d_ws;
  size_t o = 0;
  auto alloc = [&](size_t bytes) -> void* {
    void* p = ws + o;
    o += (bytes + 255) & ~(size_t)255;
    return p;
  };
  float* s_feat = (float*)alloc((size_t)NA * 64 * 4);
  float* a_s    = (float*)alloc((size_t)NA * 96 * 4);
  float* a_v    = (float*)alloc((size_t)NA * 384 * 4);
  float* sh0    = (float*)alloc((size_t)NA * 64 * 4);
  float* sh1    = (float*)alloc((size_t)NA * 64 * 4);
  float* vh0    = (float*)alloc((size_t)NA * 128 * 4);  // padded [n][32][4]
  float* vh1    = (float*)alloc((size_t)NA * 128 * 4);
  int* count    = (int*)alloc((size_t)NA * 4);
  int* offsets  = (int*)alloc((size_t)(NA + 1) * 4);
  int* sorted   = (int*)alloc((size_t)ET * 4);
  float4* rec   = (float4*)alloc((size_t)ET * 48);
  float* shb[2] = {sh0, sh1};
  float* vhb[2] = {vh0, vh1};

  // CSR build
  k_zero<<<NA / 256, 256, 0, stream>>>(count);
  k_hist<<<ET / 256, 256, 0, stream>>>(rad, bon, count);
  k_scan<<<1, 256, 0, stream>>>(count, offsets);
  k_fill<<<ET / 256, 256, 0, stream>>>(rad, bon, count, sorted);
  k_edge_pre<<<ET / 256, 256, 0, stream>>>(pos, rad, bon, sorted, rec);

  k_embed<<<NA * 64 / 256, 256, 0, stream>>>(atom_tab, types, ns0_w, cn, s_feat);
  k_agg0<<<NA / 4, 256, 0, stream>>>(bond_tab, We0, We1, offsets, (const float*)rec, s_feat, a_s, a_v);
  k_init<<<NA * 64 / 256 + NA * 32 / 256, 256, 0, stream>>>(
      a_s, s_feat, Ws0, Wself0, a_v, Wv0, shb[0], vhb[0]);

  for (int l = 0; l < 2; ++l) {
    int bin = l & 1, bout = 1 - bin;
    k_agg_layer<<<NA / 4, 256, 0, stream>>>(
        cn, bond_tab,
        We_ss + l * 16 * 64, We_vs + l * 16 * 32, We_sv + l * 16 * 64,
        We_vv + l * 16 * 32, We_vx + l * 16 * 32, ns_w + l * 96,
        offsets, (const float*)rec, shb[bin], vhb[bin], a_s, a_v);
    k_mix<<<NA * 64 / 256 + NA * 32 / 256, 256, 0, stream>>>(
        a_s, shb[bin], Wmix_s + l * 96 * 64, Wself_s + l * 64 * 64,
        a_v, vhb[bin], Wmix_v + l * 128 * 32, Wself_v + l * 32 * 32,
        ns_w + l * 96, skip_w + l * 192, skip_b + l * 192, cn, shb[bout], vhb[bout]);
  }
  k_out<<<NA * 3 / 256, 256, 0, stream>>>(vhb[0], w_out, gain, (float*)d_out);
}

// Round 6
// 596.345 us; speedup vs baseline: 1.1274x; 1.1274x over previous
//
#include <hip/hip_runtime.h>
#include <math.h>

#define NA 16384
#define ER 524288
#define EB 32768
#define ET 557056
#define INV_NORM 0.17149858514250882f   // 1/sqrt((ER+EB)/NA) = 1/sqrt(34)
#define SQRT3 1.7320508075688772f
#define RB_STEP (1.5f/9.0f)
#define BINS 512
#define DMAX 2.5f
#define INV_H ((float)BINS / DMAX)

typedef float nfloat4 __attribute__((ext_vector_type(4)));

__device__ __forceinline__ float sigmoidf_(float x) { return 1.f / (1.f + __expf(-x)); }

__device__ __forceinline__ int edge_dst(int e, const int* __restrict__ rad, const int* __restrict__ bon) {
  return (e < ER) ? rad[ER + e] : bon[EB + (e - ER)];
}

// ---------------- CSR build ----------------
__global__ void k_zero(int* __restrict__ count) {
  count[blockIdx.x * 256 + threadIdx.x] = 0;
}

__global__ void k_hist(const int* __restrict__ rad, const int* __restrict__ bon, int* __restrict__ count) {
  int e = blockIdx.x * 256 + threadIdx.x;
  atomicAdd(&count[edge_dst(e, rad, bon)], 1);
}

__global__ void k_scan(int* __restrict__ count, int* __restrict__ offsets) {
  __shared__ int part[256];
  int t = threadIdx.x;
  int base = t * 64;
  int s = 0;
  for (int j = 0; j < 64; ++j) s += count[base + j];
  part[t] = s;
  __syncthreads();
  for (int off = 1; off < 256; off <<= 1) {
    int v = (t >= off) ? part[t - off] : 0;
    __syncthreads();
    part[t] += v;
    __syncthreads();
  }
  int run = part[t] - s;  // exclusive prefix
  for (int j = 0; j < 64; ++j) {
    int c = count[base + j];
    offsets[base + j] = run;
    count[base + j] = run;  // becomes cursor for k_fill
    run += c;
  }
  if (t == 255) offsets[NA] = run;
}

__global__ void k_fill(const int* __restrict__ rad, const int* __restrict__ bon,
                       int* __restrict__ cursor, int* __restrict__ sorted) {
  int e = blockIdx.x * 256 + threadIdx.x;
  int d = edge_dst(e, rad, bon);
  int slot = atomicAdd(&cursor[d], 1);
  sorted[slot] = e;
}

// ---------------- per-edge record precompute ----------------
// record[idx] (32B, CSR slot order): {src|(isBond<<16), Y0, Y1, Y2, d, pad...}
__global__ void k_edge_pre(const float* __restrict__ pos,
                           const int* __restrict__ rad, const int* __restrict__ bon,
                           const int* __restrict__ sorted, float* __restrict__ rec8) {
  int idx = blockIdx.x * 256 + threadIdx.x;
  int e = sorted[idx];
  int src, dst, flag;
  if (e < ER) { src = rad[e]; dst = rad[ER + e]; flag = 0; }
  else        { src = bon[e - ER]; dst = bon[EB + e - ER]; flag = 1 << 16; }
  float dx = pos[src * 3] - pos[dst * 3];
  float dy = pos[src * 3 + 1] - pos[dst * 3 + 1];
  float dz = pos[src * 3 + 2] - pos[dst * 3 + 2];
  float dist = sqrtf(dx * dx + dy * dy + dz * dz + 1e-12f);
  float inv = 1.f / dist;
  float* rp = rec8 + (size_t)idx * 8;
  *(float4*)rp = make_float4(__int_as_float(src | flag), SQRT3 * dx * inv, SQRT3 * dy * inv, SQRT3 * dz * inv);
  rp[4] = dist;
}

// ---------------- radial-weight interpolation tables ----------------
// tabs layout: 5 tables of [BINS][64][4] floats:
//   t=0: agg0   {T_w0, dT_w0, T_w1, dT_w1}            (c = channel 0..63)
//   t=1: L0 S   {T_ss, dT_ss, T_sv, dT_sv}            (c = channel)
//   t=2: L0 U   c<32: {T_vs, dT, T_vv, dT}; c>=32: {T_vx, dT, 0, 0} (c = lane)
//   t=3: L1 S   t=4: L1 U
__global__ void k_build(const float* __restrict__ We0, const float* __restrict__ We1,
                        const float* __restrict__ We_ss, const float* __restrict__ We_vs,
                        const float* __restrict__ We_sv, const float* __restrict__ We_vv,
                        const float* __restrict__ We_vx, float* __restrict__ tabs) {
  int q = blockIdx.x, t = blockIdx.y, c = threadIdx.x;
  float d0 = q * (DMAX / BINS), d1 = (q + 1) * (DMAX / BINS);
  float rb0[8], rb1[8];
#pragma unroll
  for (int k = 0; k < 8; ++k) {
    float f0 = (d0 - (k + 1) * RB_STEP) * (1.f / RB_STEP);
    float f1 = (d1 - (k + 1) * RB_STEP) * (1.f / RB_STEP);
    rb0[k] = 1.12f * __expf(-f0 * f0);
    rb1[k] = 1.12f * __expf(-f1 * f1);
  }
  float a0 = 0, a1 = 0, b0 = 0, b1 = 0;
  if (t == 0 || t == 1 || t == 3) {
    const float* A = (t == 0) ? We0 : (t == 1) ? We_ss : (We_ss + 16 * 64);
    const float* B = (t == 0) ? We1 : (t == 1) ? We_sv : (We_sv + 16 * 64);
#pragma unroll
    for (int k = 0; k < 8; ++k) {
      float av = A[(8 + k) * 64 + c], bv = B[(8 + k) * 64 + c];
      a0 += rb0[k] * av; a1 += rb1[k] * av;
      b0 += rb0[k] * bv; b1 += rb1[k] * bv;
    }
  } else {
    int l = (t == 2) ? 0 : 1;
    const float* Wvs = We_vs + l * 16 * 32;
    const float* Wvv = We_vv + l * 16 * 32;
    const float* Wvx = We_vx + l * 16 * 32;
    if (c < 32) {
#pragma unroll
      for (int k = 0; k < 8; ++k) {
        float av = Wvs[(8 + k) * 32 + c], bv = Wvv[(8 + k) * 32 + c];
        a0 += rb0[k] * av; a1 += rb1[k] * av;
        b0 += rb0[k] * bv; b1 += rb1[k] * bv;
      }
    } else {
#pragma unroll
      for (int k = 0; k < 8; ++k) {
        float av = Wvx[(8 + k) * 32 + c - 32];
        a0 += rb0[k] * av; a1 += rb1[k] * av;
      }
    }
  }
  float* o = tabs + (((size_t)t * BINS + q) * 64 + c) * 4;
  o[0] = a0; o[1] = a1 - a0; o[2] = b0; o[3] = b1 - b0;
}

// ---------------- embedding ----------------
__global__ void k_embed(const float* __restrict__ atom_tab, const int* __restrict__ types,
                        const float* __restrict__ ns0_w, const float* __restrict__ cnoise,
                        float* __restrict__ s_feat) {
  int tid = blockIdx.x * 256 + threadIdx.x;
  int n = tid >> 6, c = tid & 63;
  float cn = cnoise[0];
  s_feat[tid] = atom_tab[types[n] * 64 + c] * (1.f + cn * ns0_w[c]);
}

// ---------------- initial aggregation (wave per node, lane = channel) ----------------
__global__ __launch_bounds__(256, 6) void k_agg0(
    const float* __restrict__ bond_tab,
    const float* __restrict__ We0, const float* __restrict__ We1,
    const int* __restrict__ offsets, const float* __restrict__ rec8,
    const float* __restrict__ T0, const float* __restrict__ s_feat,
    float* __restrict__ a_s, float* __restrict__ a_v) {
  int lane = threadIdx.x & 63;
  int n = blockIdx.x * 4 + (threadIdx.x >> 6);
  int c = lane;
  float w0b0 = 0, w0b1 = 0, w1b0 = 0, w1b1 = 0;
#pragma unroll
  for (int k = 0; k < 8; ++k) {
    float bt0 = bond_tab[k], bt1 = bond_tab[8 + k];
    float c0 = We0[k * 64 + c], c1 = We1[k * 64 + c];
    w0b0 += bt0 * c0; w0b1 += bt1 * c0;
    w1b0 += bt0 * c1; w1b1 += bt1 * c1;
  }
  float acc = 0, a0 = 0, a1 = 0, a2 = 0;
  int beg = __builtin_amdgcn_readfirstlane(offsets[n]);
  int end = __builtin_amdgcn_readfirstlane(offsets[n + 1]);
  for (int idx = beg; idx < end; ++idx) {
    const float* rp = rec8 + (size_t)idx * 8;
    float4 r0 = *(const float4*)rp;
    float d = rp[4];
    int senc = __float_as_int(r0.x);
    int src = senc & 0xFFFF;
    bool isB = senc >= (1 << 16);
    float fq = fminf(d * INV_H, BINS - 1.001f);
    float qf = floorf(fq);
    float frac = fq - qf;
    int q = (int)qf;
    float4 t4 = ((const float4*)(T0 + ((size_t)q << 8)))[c];
    float w0 = fmaf(frac, t4.y, t4.x) + (isB ? w0b1 : w0b0);
    float w1 = fmaf(frac, t4.w, t4.z) + (isB ? w1b1 : w1b0);
    float sv = s_feat[((size_t)src << 6) + c];
    acc += w0 * sv;
    float t = w1 * sv;
    a0 += t * r0.y; a1 += t * r0.z; a2 += t * r0.w;
  }
  a_s[n * 64 + c] = acc * INV_NORM;
  float* avp = a_v + (size_t)n * 192 + c * 3;
  avp[0] = a0 * INV_NORM; avp[1] = a1 * INV_NORM; avp[2] = a2 * INV_NORM;
}

// ---------------- initial projections (merged sh + vh) ----------------
__global__ void k_init(const float* __restrict__ a_s, const float* __restrict__ s_feat,
                       const float* __restrict__ Ws0, const float* __restrict__ Wself0,
                       const float* __restrict__ a_v, const float* __restrict__ Wv0,
                       float* __restrict__ sh, float* __restrict__ vh) {
  int b = blockIdx.x;
  if (b < NA * 64 / 256) {
    int tid = b * 256 + threadIdx.x;
    int n = tid >> 6, d = tid & 63;
    float acc = 0;
    const float* as = a_s + n * 64;
    const float* sp = s_feat + n * 64;
    for (int c = 0; c < 64; ++c)
      acc += as[c] * Ws0[c * 64 + d] + sp[c] * Wself0[c * 64 + d];
    sh[tid] = acc;
  } else {
    int tid = (b - NA * 64 / 256) * 256 + threadIdx.x;
    int n = tid >> 5, d = tid & 31;
    float a0 = 0, a1 = 0, a2 = 0;
    const float* av = a_v + (size_t)n * 192;
    for (int c = 0; c < 64; ++c) {
      float w = Wv0[c * 32 + d];
      a0 += av[c * 3] * w; a1 += av[c * 3 + 1] * w; a2 += av[c * 3 + 2] * w;
    }
    float* o = vh + (size_t)n * 128 + d * 4;  // padded [n][32][4]
    o[0] = a0; o[1] = a1; o[2] = a2;
  }
}

// ---------------- layer aggregation (wave per node) ----------------
__global__ __launch_bounds__(256, 6) void k_agg_layer(
    const float* __restrict__ cnoise, const float* __restrict__ bond_tab,
    const float* __restrict__ Wss, const float* __restrict__ Wvs,
    const float* __restrict__ Wsv, const float* __restrict__ Wvv,
    const float* __restrict__ Wvx, const float* __restrict__ nsw,
    const int* __restrict__ offsets, const float* __restrict__ rec8,
    const float* __restrict__ TS, const float* __restrict__ TU,
    const float* __restrict__ sh_in, const float* __restrict__ vh_in,
    float* __restrict__ a_s, float* __restrict__ a_v) {
  int lane = threadIdx.x & 63;
  int n = blockIdx.x * 4 + (threadIdx.x >> 6);
  int c = lane;
  int vc = lane & 31;
  bool low = lane < 32;
  float cn = cnoise[0];

  float bss0 = 0, bss1 = 0, bsv0 = 0, bsv1 = 0, bva0 = 0, bva1 = 0, bvb0 = 0, bvb1 = 0;
#pragma unroll
  for (int k = 0; k < 8; ++k) {
    float wss_lo = Wss[k * 64 + c];
    float wsv_lo = Wsv[k * 64 + c];
    float wa_lo = low ? Wvs[k * 32 + vc] : Wvx[k * 32 + vc];
    float wb_lo = low ? Wvv[k * 32 + vc] : 0.f;
    float bt0 = bond_tab[k], bt1 = bond_tab[8 + k];
    bss0 += bt0 * wss_lo; bss1 += bt1 * wss_lo;
    bsv0 += bt0 * wsv_lo; bsv1 += bt1 * wsv_lo;
    bva0 += bt0 * wa_lo;  bva1 += bt1 * wa_lo;
    bvb0 += bt0 * wb_lo;  bvb1 += bt1 * wb_lo;
  }
  float scale_s = 1.f + cn * nsw[c];
  float scale_v = 1.f + cn * nsw[64 + vc];

  float ms = 0;                    // sum w_ss*sh        (scale_s folded at store)
  float av0 = 0, av1 = 0, av2 = 0; // sum w_sv*sh*Y      (scale_s folded)
  float ms2 = 0;                   // low: sum w_vs*(v.Y) (scale_v folded)
  float b0 = 0, b1 = 0, b2 = 0;    // low: w_vv*v ; high: w_vx*cross(v,Y) (scale_v folded)
  int beg = __builtin_amdgcn_readfirstlane(offsets[n]);
  int end = __builtin_amdgcn_readfirstlane(offsets[n + 1]);
  for (int idx = beg; idx < end; ++idx) {
    const float* rp = rec8 + (size_t)idx * 8;
    float4 r0 = *(const float4*)rp;
    float d = rp[4];
    int senc = __float_as_int(r0.x);
    int src = senc & 0xFFFF;
    bool isB = senc >= (1 << 16);
    float y0 = r0.y, y1 = r0.z, y2 = r0.w;
    float fq = fminf(d * INV_H, BINS - 1.001f);
    float qf = floorf(fq);
    float frac = fq - qf;
    int q = (int)qf;
    float4 s4 = ((const float4*)(TS + ((size_t)q << 8)))[c];
    float4 u4 = ((const float4*)(TU + ((size_t)q << 8)))[lane];
    float wS  = fmaf(frac, s4.y, s4.x) + (isB ? bss1 : bss0);
    float wSV = fmaf(frac, s4.w, s4.z) + (isB ? bsv1 : bsv0);
    float wA  = fmaf(frac, u4.y, u4.x) + (isB ? bva1 : bva0);
    float wB  = fmaf(frac, u4.w, u4.z) + (isB ? bvb1 : bvb0);
    float ss = sh_in[((size_t)src << 6) + c];
    nfloat4 v4 = ((const nfloat4*)(vh_in + ((size_t)src << 7)))[vc];
    float v0 = v4.x, v1 = v4.y, v2 = v4.z;
    ms += wS * ss;
    float t = wSV * ss;
    av0 += t * y0; av1 += t * y1; av2 += t * y2;
    float vdot = v0 * y0 + v1 * y1 + v2 * y2;
    ms2 += wA * vdot;  // garbage on high lanes, never written
    float cx = v1 * y2 - v2 * y1;
    float cy = v2 * y0 - v0 * y2;
    float cz = v0 * y1 - v1 * y0;
    float m0 = low ? v0 : cx;
    float m1 = low ? v1 : cy;
    float m2 = low ? v2 : cz;
    float wM = low ? wB : wA;
    b0 += wM * m0; b1 += wM * m1; b2 += wM * m2;
  }
  float fs = scale_s * INV_NORM;
  float fv = scale_v * INV_NORM;
  a_s[n * 96 + c] = ms * fs;
  float* avn = a_v + (size_t)n * 384;
  avn[c * 3] = av0 * fs; avn[c * 3 + 1] = av1 * fs; avn[c * 3 + 2] = av2 * fs;
  if (low) {
    a_s[n * 96 + 64 + vc] = ms2 * fv;
    avn[(64 + vc) * 3] = b0 * fv;
    avn[(64 + vc) * 3 + 1] = b1 * fv;
    avn[(64 + vc) * 3 + 2] = b2 * fv;
  } else {
    avn[(96 + vc) * 3] = b0 * fv;
    avn[(96 + vc) * 3 + 1] = b1 * fv;
    avn[(96 + vc) * 3 + 2] = b2 * fv;
  }
}

// ---------------- mixing / self / skip (merged s + v) ----------------
__global__ void k_mix(const float* __restrict__ a_s, const float* __restrict__ sh_in,
                      const float* __restrict__ Wmix_s, const float* __restrict__ Wself_s,
                      const float* __restrict__ a_v, const float* __restrict__ vh_in,
                      const float* __restrict__ Wmix_v, const float* __restrict__ Wself_v,
                      const float* __restrict__ nsw, const float* __restrict__ skw,
                      const float* __restrict__ skb, const float* __restrict__ cnoise,
                      float* __restrict__ sh_out, float* __restrict__ vh_out) {
  int b = blockIdx.x;
  float cn = cnoise[0];
  if (b < NA * 64 / 256) {
    int tid = b * 256 + threadIdx.x;
    int n = tid >> 6, d = tid & 63;
    float acc = 0;
    const float* as = a_s + n * 96;
    for (int cc = 0; cc < 96; ++cc) acc += as[cc] * Wmix_s[cc * 64 + d];
    const float* sp = sh_in + n * 64;
    for (int cc = 0; cc < 64; ++cc) acc += sp[cc] * (1.f + cn * nsw[cc]) * Wself_s[cc * 64 + d];
    float g1 = sigmoidf_(skb[d] + cn * skw[d]);
    float g2 = sigmoidf_(skb[64 + d] + cn * skw[64 + d]);
    sh_out[tid] = g1 * sh_in[tid] + g2 * acc;
  } else {
    int tid = (b - NA * 64 / 256) * 256 + threadIdx.x;
    int n = tid >> 5, d = tid & 31;
    float a0 = 0, a1 = 0, a2 = 0;
    const float* av = a_v + (size_t)n * 384;
    for (int cc = 0; cc < 128; ++cc) {
      float w = Wmix_v[cc * 32 + d];
      a0 += av[cc * 3] * w; a1 += av[cc * 3 + 1] * w; a2 += av[cc * 3 + 2] * w;
    }
    const float* vp = vh_in + (size_t)n * 128;
    for (int cc = 0; cc < 32; ++cc) {
      float w = Wself_v[cc * 32 + d] * (1.f + cn * nsw[64 + cc]);
      a0 += vp[cc * 4] * w; a1 += vp[cc * 4 + 1] * w; a2 += vp[cc * 4 + 2] * w;
    }
    float g3 = sigmoidf_(skb[128 + d] + cn * skw[128 + d]);
    float g4 = sigmoidf_(skb[160 + d] + cn * skw[160 + d]);
    float* o = vh_out + (size_t)n * 128 + d * 4;
    const float* vi = vh_in + (size_t)n * 128 + d * 4;
    o[0] = g3 * vi[0] + g4 * a0;
    o[1] = g3 * vi[1] + g4 * a1;
    o[2] = g3 * vi[2] + g4 * a2;
  }
}

// ---------------- output ----------------
__global__ void k_out(const float* __restrict__ vh, const float* __restrict__ w_out,
                      const float* __restrict__ gain, float* __restrict__ out) {
  int tid = blockIdx.x * 256 + threadIdx.x;  // < NA*3
  int n = tid / 3, i = tid - n * 3;
  float acc = 0;
  for (int c = 0; c < 32; ++c) acc += vh[(size_t)n * 128 + c * 4 + i] * w_out[c];
  out[tid] = acc * gain[0];
}

extern "C" void kernel_launch(void* const* d_in, const int* in_sizes, int n_in,
                              void* d_out, int out_size, void* d_ws, size_t ws_size,
                              hipStream_t stream) {
  (void)in_sizes; (void)n_in; (void)out_size; (void)ws_size;
  const float* pos     = (const float*)d_in[0];
  const float* cn      = (const float*)d_in[1];
  const int*   types   = (const int*)d_in[2];
  const int*   rad     = (const int*)d_in[3];
  const int*   bon     = (const int*)d_in[4];
  const float* atom_tab= (const float*)d_in[5];
  const float* bond_tab= (const float*)d_in[6];
  const float* ns0_w   = (const float*)d_in[7];
  const float* We0     = (const float*)d_in[8];
  const float* We1     = (const float*)d_in[9];
  const float* Wself0  = (const float*)d_in[10];
  const float* Ws0     = (const float*)d_in[11];
  const float* Wv0     = (const float*)d_in[12];
  const float* ns_w    = (const float*)d_in[13];
  const float* We_ss   = (const float*)d_in[14];
  const float* We_vs   = (const float*)d_in[15];
  const float* We_sv   = (const float*)d_in[16];
  const float* We_vv   = (const float*)d_in[17];
  const float* We_vx   = (const float*)d_in[18];
  const float* Wmix_s  = (const float*)d_in[19];
  const float* Wmix_v  = (const float*)d_in[20];
  const float* Wself_s = (const float*)d_in[21];
  const float* Wself_v = (const float*)d_in[22];
  const float* skip_w  = (const float*)d_in[23];
  const float* skip_b  = (const float*)d_in[24];
  const float* w_out   = (const float*)d_in[25];
  const float* gain    = (const float*)d_in[26];

  char* ws = (char*)d_ws;
  size_t o = 0;
  auto alloc = [&](size_t bytes) -> void* {
    void* p = ws + o;
    o += (bytes + 255) & ~(size_t)255;
    return p;
  };
  float* s_feat = (float*)alloc((size_t)NA * 64 * 4);
  float* a_s    = (float*)alloc((size_t)NA * 96 * 4);
  float* a_v    = (float*)alloc((size_t)NA * 384 * 4);
  float* sh0    = (float*)alloc((size_t)NA * 64 * 4);
  float* sh1    = (float*)alloc((size_t)NA * 64 * 4);
  float* vh0    = (float*)alloc((size_t)NA * 128 * 4);  // padded [n][32][4]
  float* vh1    = (float*)alloc((size_t)NA * 128 * 4);
  int* count    = (int*)alloc((size_t)NA * 4);
  int* offsets  = (int*)alloc((size_t)(NA + 1) * 4);
  int* sorted   = (int*)alloc((size_t)ET * 4);
  float* rec8   = (float*)alloc((size_t)ET * 32);
  float* tabs   = (float*)alloc((size_t)5 * BINS * 64 * 4 * 4);
  float* shb[2] = {sh0, sh1};
  float* vhb[2] = {vh0, vh1};

  // CSR build + tables
  k_zero<<<NA / 256, 256, 0, stream>>>(count);
  k_hist<<<ET / 256, 256, 0, stream>>>(rad, bon, count);
  k_scan<<<1, 256, 0, stream>>>(count, offsets);
  k_fill<<<ET / 256, 256, 0, stream>>>(rad, bon, count, sorted);
  k_edge_pre<<<ET / 256, 256, 0, stream>>>(pos, rad, bon, sorted, rec8);
  k_build<<<dim3(BINS, 5), 64, 0, stream>>>(We0, We1, We_ss, We_vs, We_sv, We_vv, We_vx, tabs);

  k_embed<<<NA * 64 / 256, 256, 0, stream>>>(atom_tab, types, ns0_w, cn, s_feat);
  k_agg0<<<NA / 4, 256, 0, stream>>>(bond_tab, We0, We1, offsets, rec8, tabs, s_feat, a_s, a_v);
  k_init<<<NA * 64 / 256 + NA * 32 / 256, 256, 0, stream>>>(
      a_s, s_feat, Ws0, Wself0, a_v, Wv0, shb[0], vhb[0]);

  for (int l = 0; l < 2; ++l) {
    int bin = l & 1, bout = 1 - bin;
    const float* TS = tabs + (size_t)(1 + 2 * l) * BINS * 256;
    const float* TU = tabs + (size_t)(2 + 2 * l) * BINS * 256;
    k_agg_layer<<<NA / 4, 256, 0, stream>>>(
        cn, bond_tab,
        We_ss + l * 16 * 64, We_vs + l * 16 * 32, We_sv + l * 16 * 64,
        We_vv + l * 16 * 32, We_vx + l * 16 * 32, ns_w + l * 96,
        offsets, rec8, TS, TU, shb[bin], vhb[bin], a_s, a_v);
    k_mix<<<NA * 64 / 256 + NA * 32 / 256, 256, 0, stream>>>(
        a_s, shb[bin], Wmix_s + l * 96 * 64, Wself_s + l * 64 * 64,
        a_v, vhb[bin], Wmix_v + l * 128 * 32, Wself_v + l * 32 * 32,
        ns_w + l * 96, skip_w + l * 192, skip_b + l * 192, cn, shb[bout], vhb[bout]);
  }
  k_out<<<NA * 3 / 256, 256, 0, stream>>>(vhb[0], w_out, gain, (float*)d_out);
}